// Round 1
// baseline (839.497 us; speedup 1.0000x reference)
//
#include <hip/hip_runtime.h>
#include <cmath>

#define NPTS 10000
#define NBATCH 8
#define NFEAT 16
#define DDIM 128
#define NBINS 20
#define BINSZ 500
#define KSEL 5
#define EDGES_PER_BATCH (NPTS*KSEL)        // 50000
#define EDGE_TOT (NBATCH*EDGES_PER_BATCH)  // 400000
#define TOTPTS (NBATCH*NPTS)               // 80000

__global__ void k_zero_hist(int* hist) {
    int t = threadIdx.x;
    if (t < NBATCH*NBINS) hist[t] = 0;
}

// enc = ELU(X@W1+b1)@W2+b2 ; 32 points per block, 256 threads
__global__ __launch_bounds__(256) void k_enc(const float* __restrict__ X,
        const float* __restrict__ W1, const float* __restrict__ b1,
        const float* __restrict__ W2, const float* __restrict__ b2,
        float* __restrict__ enc) {
    __shared__ float hT[128*36];   // hT[k*36+p], padded stride 36 keeps float4 alignment
    const int tid = threadIdx.x;
    const int P0 = blockIdx.x * 32;
    // phase 1: hidden, ELU
    #pragma unroll
    for (int i = 0; i < 16; ++i) {
        int idx = i*256 + tid;
        int p = idx >> 7;         // 0..31
        int j = idx & 127;
        const float* xr = X + (size_t)(P0 + p)*NFEAT;
        float h = b1[j];
        #pragma unroll
        for (int f = 0; f < 16; ++f) h += xr[f] * W1[f*128 + j];
        h = (h > 0.f) ? h : expm1f(h);   // jax.nn.elu
        hT[j*36 + p] = h;
    }
    __syncthreads();
    // phase 2: 4x4 register tile per thread
    const int jt = tid & 31, pt = tid >> 5;
    const int j0 = jt*4, p0 = pt*4;
    float acc[4][4];
    #pragma unroll
    for (int ep = 0; ep < 4; ++ep)
        #pragma unroll
        for (int ej = 0; ej < 4; ++ej) acc[ep][ej] = b2[j0+ej];
    for (int k = 0; k < 128; ++k) {
        float4 hv = *(const float4*)&hT[k*36 + p0];
        float4 wv = *(const float4*)&W2[k*128 + j0];
        float hvv[4] = {hv.x,hv.y,hv.z,hv.w};
        float wvv[4] = {wv.x,wv.y,wv.z,wv.w};
        #pragma unroll
        for (int ep = 0; ep < 4; ++ep)
            #pragma unroll
            for (int ej = 0; ej < 4; ++ej) acc[ep][ej] += hvv[ep]*wvv[ej];
    }
    #pragma unroll
    for (int ep = 0; ep < 4; ++ep) {
        float4 o = {acc[ep][0],acc[ep][1],acc[ep][2],acc[ep][3]};
        *(float4*)&enc[(size_t)(P0+p0+ep)*128 + j0] = o;
    }
}

// mul = enc @ R[:, :10]; bin = argmax([mul, -mul]) first-max-wins; histogram
__global__ __launch_bounds__(256) void k_bins(const float* __restrict__ enc,
        const float* __restrict__ R, int* __restrict__ binIdx, int* __restrict__ hist) {
    __shared__ float Rl[128*10];
    const int tid = threadIdx.x;
    for (int idx = tid; idx < 1280; idx += 256) {
        int d = idx / 10, i = idx % 10;
        Rl[idx] = R[d*100 + i];     // R is (128,100) row-major; Rl[d*10+i]
    }
    __syncthreads();
    int gp = blockIdx.x*256 + tid;
    if (gp >= TOTPTS) return;
    float acc[10];
    #pragma unroll
    for (int i = 0; i < 10; ++i) acc[i] = 0.f;
    const float4* er = (const float4*)(enc + (size_t)gp*128);
    for (int d4 = 0; d4 < 32; ++d4) {
        float4 e4 = er[d4];
        float ev[4] = {e4.x,e4.y,e4.z,e4.w};
        #pragma unroll
        for (int q = 0; q < 4; ++q) {
            const float* rr = &Rl[(d4*4+q)*10];
            #pragma unroll
            for (int i = 0; i < 10; ++i) acc[i] += ev[q]*rr[i];
        }
    }
    // argmax over [acc[0..9], -acc[0..9]], first occurrence wins (strict >)
    float best = acc[0]; int bi = 0;
    #pragma unroll
    for (int i = 1; i < 10; ++i) if (acc[i] > best) { best = acc[i]; bi = i; }
    #pragma unroll
    for (int i = 0; i < 10; ++i) { float v = -acc[i]; if (v > best) { best = v; bi = 10+i; } }
    binIdx[gp] = bi;
    atomicAdd(&hist[(gp/NPTS)*NBINS + bi], 1);
}

// stable counting-sort scatter: one block per (batch,bin)
__global__ __launch_bounds__(256) void k_sort(const int* __restrict__ binIdx,
        const int* __restrict__ hist, int* __restrict__ sortedIdx) {
    const int b = blockIdx.x / NBINS;
    const int bin = blockIdx.x % NBINS;
    const int tid = threadIdx.x;
    __shared__ int wtot[4];
    int off = 0;
    for (int k = 0; k < bin; ++k) off += hist[b*NBINS + k];
    const int* bptr = binIdx + b*NPTS;
    int* sptr = sortedIdx + b*NPTS;
    const int lane = tid & 63, wid = tid >> 6;
    for (int c = 0; c < 40; ++c) {
        int i = c*256 + tid;
        bool pred = (i < NPTS) && (bptr[i] == bin);
        unsigned long long mask = __ballot(pred);
        int rank = __popcll(mask & ((1ULL << lane) - 1ULL));
        if (lane == 0) wtot[wid] = __popcll(mask);
        __syncthreads();
        int prefix = 0;
        #pragma unroll
        for (int w = 0; w < 4; ++w) prefix += (w < wid) ? wtot[w] : 0;
        int total = wtot[0]+wtot[1]+wtot[2]+wtot[3];
        if (pred) sptr[off + prefix + rank] = i;
        off += total;
        __syncthreads();
    }
}

// per 500-group gram + top-5 (lax.top_k tie semantics) + sort-by-dst + write src/dst
// grid: (group, half) -> 250 rows per block, 256 threads
__global__ __launch_bounds__(256) void k_gram(const float* __restrict__ enc,
        const int* __restrict__ sortedIdx, int* __restrict__ wsDst,
        float* __restrict__ wsVal, float* __restrict__ out) {
    __shared__ float tile[100*128];
    __shared__ int gIdx[500];
    const int tid = threadIdx.x;
    const int grp = blockIdx.x >> 1, half = blockIdx.x & 1;
    const int b = grp / NBINS, g = grp % NBINS;
    for (int i = tid; i < 500; i += 256)
        gIdx[i] = sortedIdx[b*NPTS + g*500 + i];
    __syncthreads();
    const bool active = tid < 250;
    const int r = half*250 + tid;
    float4 rowv[32];
    if (active) {
        const float4* rv = (const float4*)(enc + (size_t)(b*NPTS + gIdx[r])*128);
        #pragma unroll
        for (int d = 0; d < 32; ++d) rowv[d] = rv[d];
    }
    float tv0=-3.4e38f,tv1=-3.4e38f,tv2=-3.4e38f,tv3=-3.4e38f,tv4=-3.4e38f;
    int tp0=0,tp1=0,tp2=0,tp3=0,tp4=0;
    for (int t = 0; t < 5; ++t) {
        __syncthreads();
        for (int idx = tid; idx < 3200; idx += 256) {
            int c = idx >> 5, d4 = idx & 31;
            float4 v = ((const float4*)(enc + (size_t)(b*NPTS + gIdx[t*100 + c])*128))[d4];
            *(float4*)&tile[c*128 + d4*4] = v;
        }
        __syncthreads();
        if (active) {
            for (int cc = 0; cc < 100; ++cc) {
                const float4* col4 = (const float4*)&tile[cc*128];
                float a0=0.f,a1=0.f,a2=0.f,a3=0.f;
                #pragma unroll
                for (int d = 0; d < 32; ++d) {
                    float4 cv = col4[d];
                    a0 += cv.x*rowv[d].x; a1 += cv.y*rowv[d].y;
                    a2 += cv.z*rowv[d].z; a3 += cv.w*rowv[d].w;
                }
                float v = (a0+a1)+(a2+a3);
                int cpos = t*100 + cc;
                // strict > insertion, ascending cpos => lower index wins ties (lax.top_k)
                if (v > tv4) {
                    if (v > tv3) { tv4=tv3; tp4=tp3;
                        if (v > tv2) { tv3=tv2; tp3=tp2;
                            if (v > tv1) { tv2=tv1; tp2=tp1;
                                if (v > tv0) { tv1=tv0; tp1=tp0; tv0=v; tp0=cpos; }
                                else { tv1=v; tp1=cpos; }
                            } else { tv2=v; tp2=cpos; }
                        } else { tv3=v; tp3=cpos; }
                    } else { tv4=v; tp4=cpos; }
                }
            }
        }
    }
    if (!active) return;
    int dd[5] = {gIdx[tp0],gIdx[tp1],gIdx[tp2],gIdx[tp3],gIdx[tp4]};
    float vv[5];
    vv[0] = 1.f/(1.f+expf(-tv0)); vv[1] = 1.f/(1.f+expf(-tv1));
    vv[2] = 1.f/(1.f+expf(-tv2)); vv[3] = 1.f/(1.f+expf(-tv3));
    vv[4] = 1.f/(1.f+expf(-tv4));
    // sort 5 (dst,val) pairs by dst ascending — 9-comparator network (keys unique)
    #define CSWAP(i,j) { if (dd[i] > dd[j]) { int td=dd[i];dd[i]=dd[j];dd[j]=td; \
                         float tf=vv[i];vv[i]=vv[j];vv[j]=tf; } }
    CSWAP(0,1) CSWAP(3,4) CSWAP(2,4) CSWAP(2,3) CSWAP(1,4)
    CSWAP(0,3) CSWAP(0,2) CSWAP(1,3) CSWAP(1,2)
    #undef CSWAP
    int src = gIdx[r];
    int base = b*EDGES_PER_BATCH + src*5;
    #pragma unroll
    for (int e = 0; e < 5; ++e) {
        wsDst[base+e] = dd[e];
        wsVal[base+e] = vv[e];
        out[EDGE_TOT   + base + e] = (float)src;   // src_idx section
        out[2*EDGE_TOT + base + e] = (float)dd[e]; // dst_idx section
    }
}

// edge MLP: one thread handles the 5 edges of one src (shares x_src partial)
__global__ __launch_bounds__(256) void k_edge(const float* __restrict__ X,
        const float* __restrict__ W1, const float* __restrict__ b1,
        const float* __restrict__ W2, const float* __restrict__ b2,
        const int* __restrict__ wsDst, const float* __restrict__ wsVal,
        float* __restrict__ out) {
    __shared__ float w1t[128*36];   // transposed W1: w1t[j*36+f], f<33
    __shared__ float b1l[128];
    __shared__ float w2l[128];
    const int tid = threadIdx.x;
    for (int idx = tid; idx < 33*128; idx += 256) {
        int f = idx >> 7, j = idx & 127;
        w1t[j*36 + f] = W1[idx];
    }
    if (tid < 128) { b1l[tid] = b1[tid]; w2l[tid] = W2[tid]; }
    __syncthreads();
    int s = blockIdx.x*256 + tid;
    if (s >= TOTPTS) return;
    const int b = s / NPTS;
    const int sl = s % NPTS;
    const int base = b*EDGES_PER_BATCH + sl*5;
    float4 xs[4];
    {
        const float4* xp = (const float4*)(X + (size_t)s*NFEAT);
        #pragma unroll
        for (int q = 0; q < 4; ++q) xs[q] = xp[q];
    }
    int dste[5]; float vale[5]; float4 xd[5][4];
    #pragma unroll
    for (int e = 0; e < 5; ++e) {
        dste[e] = wsDst[base+e];
        vale[e] = wsVal[base+e];
        const float4* xp = (const float4*)(X + (size_t)(b*NPTS + dste[e])*NFEAT);
        #pragma unroll
        for (int q = 0; q < 4; ++q) xd[e][q] = xp[q];
    }
    float acc[5] = {0.f,0.f,0.f,0.f,0.f};
    for (int j = 0; j < 128; ++j) {
        const float* wr = &w1t[j*36];
        float sh = b1l[j];
        #pragma unroll
        for (int q = 0; q < 4; ++q) {
            float4 w = ((const float4*)wr)[q];
            sh += xs[q].x*w.x + xs[q].y*w.y + xs[q].z*w.z + xs[q].w*w.w;
        }
        float w32 = wr[32];
        float w2j = w2l[j];
        #pragma unroll
        for (int e = 0; e < 5; ++e) {
            float h = sh;
            #pragma unroll
            for (int q = 0; q < 4; ++q) {
                float4 w = ((const float4*)(wr+16))[q];
                h += xd[e][q].x*w.x + xd[e][q].y*w.y + xd[e][q].z*w.z + xd[e][q].w*w.w;
            }
            h += vale[e]*w32;
            h = (h > 0.f) ? h : expm1f(h);   // ELU
            acc[e] += h * w2j;
        }
    }
    float b2v = b2[0];
    #pragma unroll
    for (int e = 0; e < 5; ++e) {
        out[base + e] = 1.f/(1.f + expf(-(acc[e] + b2v)));  // edge_vals section
    }
}

extern "C" void kernel_launch(void* const* d_in, const int* in_sizes, int n_in,
                              void* d_out, int out_size, void* d_ws, size_t ws_size,
                              hipStream_t stream) {
    const float* X   = (const float*)d_in[0];
    const float* We1 = (const float*)d_in[1];
    const float* be1 = (const float*)d_in[2];
    const float* We2 = (const float*)d_in[3];
    const float* be2 = (const float*)d_in[4];
    const float* Wd1 = (const float*)d_in[5];
    const float* bd1 = (const float*)d_in[6];
    const float* Wd2 = (const float*)d_in[7];
    const float* bd2 = (const float*)d_in[8];
    const float* R   = (const float*)d_in[9];
    float* out = (float*)d_out;

    // workspace layout (~44.8 MB)
    float* enc      = (float*)d_ws;                       // 80000*128 f32
    int*   binIdx   = (int*)(enc + (size_t)TOTPTS*128);   // 80000
    int*   sortedIdx= binIdx + TOTPTS;                    // 80000
    int*   hist     = sortedIdx + TOTPTS;                 // 160
    int*   wsDst    = hist + NBATCH*NBINS;                // 400000
    float* wsVal    = (float*)(wsDst + EDGE_TOT);         // 400000

    k_zero_hist<<<1, 256, 0, stream>>>(hist);
    k_enc <<<TOTPTS/32, 256, 0, stream>>>(X, We1, be1, We2, be2, enc);
    k_bins<<<(TOTPTS+255)/256, 256, 0, stream>>>(enc, R, binIdx, hist);
    k_sort<<<NBATCH*NBINS, 256, 0, stream>>>(binIdx, hist, sortedIdx);
    k_gram<<<NBATCH*NBINS*2, 256, 0, stream>>>(enc, sortedIdx, wsDst, wsVal, out);
    k_edge<<<(TOTPTS+255)/256, 256, 0, stream>>>(X, Wd1, bd1, Wd2, bd2, wsDst, wsVal, out);
}

// Round 2
// 599.447 us; speedup vs baseline: 1.4005x; 1.4005x over previous
//
#include <hip/hip_runtime.h>
#include <cmath>

#define NPTS 10000
#define NBATCH 8
#define NFEAT 16
#define DDIM 128
#define NBINS 20
#define BINSZ 500
#define KSEL 5
#define EDGES_PER_BATCH (NPTS*KSEL)        // 50000
#define EDGE_TOT (NBATCH*EDGES_PER_BATCH)  // 400000
#define TOTPTS (NBATCH*NPTS)               // 80000

__global__ void k_zero_hist(int* hist) {
    int t = threadIdx.x;
    if (t < NBATCH*NBINS) hist[t] = 0;
}

// enc = ELU(X@W1+b1)@W2+b2 ; 32 points per block, 256 threads
__global__ __launch_bounds__(256) void k_enc(const float* __restrict__ X,
        const float* __restrict__ W1, const float* __restrict__ b1,
        const float* __restrict__ W2, const float* __restrict__ b2,
        float* __restrict__ enc) {
    __shared__ float hT[128*36];
    const int tid = threadIdx.x;
    const int P0 = blockIdx.x * 32;
    #pragma unroll
    for (int i = 0; i < 16; ++i) {
        int idx = i*256 + tid;
        int p = idx >> 7;
        int j = idx & 127;
        const float* xr = X + (size_t)(P0 + p)*NFEAT;
        float h = b1[j];
        #pragma unroll
        for (int f = 0; f < 16; ++f) h += xr[f] * W1[f*128 + j];
        h = (h > 0.f) ? h : expm1f(h);
        hT[j*36 + p] = h;
    }
    __syncthreads();
    const int jt = tid & 31, pt = tid >> 5;
    const int j0 = jt*4, p0 = pt*4;
    float acc[4][4];
    #pragma unroll
    for (int ep = 0; ep < 4; ++ep)
        #pragma unroll
        for (int ej = 0; ej < 4; ++ej) acc[ep][ej] = b2[j0+ej];
    for (int k = 0; k < 128; ++k) {
        float4 hv = *(const float4*)&hT[k*36 + p0];
        float4 wv = *(const float4*)&W2[k*128 + j0];
        float hvv[4] = {hv.x,hv.y,hv.z,hv.w};
        float wvv[4] = {wv.x,wv.y,wv.z,wv.w};
        #pragma unroll
        for (int ep = 0; ep < 4; ++ep)
            #pragma unroll
            for (int ej = 0; ej < 4; ++ej) acc[ep][ej] += hvv[ep]*wvv[ej];
    }
    #pragma unroll
    for (int ep = 0; ep < 4; ++ep) {
        float4 o = {acc[ep][0],acc[ep][1],acc[ep][2],acc[ep][3]};
        *(float4*)&enc[(size_t)(P0+p0+ep)*128 + j0] = o;
    }
}

// mul = enc @ R[:, :10]; bin = argmax([mul, -mul]) first-max-wins; histogram
__global__ __launch_bounds__(256) void k_bins(const float* __restrict__ enc,
        const float* __restrict__ R, int* __restrict__ binIdx, int* __restrict__ hist) {
    __shared__ float Rl[128*10];
    const int tid = threadIdx.x;
    for (int idx = tid; idx < 1280; idx += 256) {
        int d = idx / 10, i = idx % 10;
        Rl[idx] = R[d*100 + i];
    }
    __syncthreads();
    int gp = blockIdx.x*256 + tid;
    if (gp >= TOTPTS) return;
    float acc[10];
    #pragma unroll
    for (int i = 0; i < 10; ++i) acc[i] = 0.f;
    const float4* er = (const float4*)(enc + (size_t)gp*128);
    for (int d4 = 0; d4 < 32; ++d4) {
        float4 e4 = er[d4];
        float ev[4] = {e4.x,e4.y,e4.z,e4.w};
        #pragma unroll
        for (int q = 0; q < 4; ++q) {
            const float* rr = &Rl[(d4*4+q)*10];
            #pragma unroll
            for (int i = 0; i < 10; ++i) acc[i] += ev[q]*rr[i];
        }
    }
    float best = acc[0]; int bi = 0;
    #pragma unroll
    for (int i = 1; i < 10; ++i) if (acc[i] > best) { best = acc[i]; bi = i; }
    #pragma unroll
    for (int i = 0; i < 10; ++i) { float v = -acc[i]; if (v > best) { best = v; bi = 10+i; } }
    binIdx[gp] = bi;
    atomicAdd(&hist[(gp/NPTS)*NBINS + bi], 1);
}

// stable counting-sort scatter: one block per (batch,bin)
__global__ __launch_bounds__(256) void k_sort(const int* __restrict__ binIdx,
        const int* __restrict__ hist, int* __restrict__ sortedIdx) {
    const int b = blockIdx.x / NBINS;
    const int bin = blockIdx.x % NBINS;
    const int tid = threadIdx.x;
    __shared__ int wtot[4];
    int off = 0;
    for (int k = 0; k < bin; ++k) off += hist[b*NBINS + k];
    const int* bptr = binIdx + b*NPTS;
    int* sptr = sortedIdx + b*NPTS;
    const int lane = tid & 63, wid = tid >> 6;
    for (int c = 0; c < 40; ++c) {
        int i = c*256 + tid;
        bool pred = (i < NPTS) && (bptr[i] == bin);
        unsigned long long mask = __ballot(pred);
        int rank = __popcll(mask & ((1ULL << lane) - 1ULL));
        if (lane == 0) wtot[wid] = __popcll(mask);
        __syncthreads();
        int prefix = 0;
        #pragma unroll
        for (int w = 0; w < 4; ++w) prefix += (w < wid) ? wtot[w] : 0;
        int total = wtot[0]+wtot[1]+wtot[2]+wtot[3];
        if (pred) sptr[off + prefix + rank] = i;
        off += total;
        __syncthreads();
    }
}

// insert (v,p) into sorted-desc 5-list, strict > (candidates arrive in ascending p)
#define INS_STRICT(VV,PP,v,p) do { \
  if ((v) > VV[4]) { \
    if ((v) > VV[3]) { VV[4]=VV[3]; PP[4]=PP[3]; \
      if ((v) > VV[2]) { VV[3]=VV[2]; PP[3]=PP[2]; \
        if ((v) > VV[1]) { VV[2]=VV[1]; PP[2]=PP[1]; \
          if ((v) > VV[0]) { VV[1]=VV[0]; PP[1]=PP[0]; VV[0]=(v); PP[0]=(p); } \
          else { VV[1]=(v); PP[1]=(p); } } \
        else { VV[2]=(v); PP[2]=(p); } } \
      else { VV[3]=(v); PP[3]=(p); } } \
    else { VV[4]=(v); PP[4]=(p); } } } while(0)

// tie-aware better-than: (v desc, p asc) — exact lax.top_k semantics
#define BT(va,pa,vb,pb) (((va) > (vb)) || (((va) == (vb)) && ((pa) < (pb))))
#define INS_TIE(VV,PP,v,p) do { \
  if (BT(v,p,VV[4],PP[4])) { \
    if (BT(v,p,VV[3],PP[3])) { VV[4]=VV[3]; PP[4]=PP[3]; \
      if (BT(v,p,VV[2],PP[2])) { VV[3]=VV[2]; PP[3]=PP[2]; \
        if (BT(v,p,VV[1],PP[1])) { VV[2]=VV[1]; PP[2]=PP[1]; \
          if (BT(v,p,VV[0],PP[0])) { VV[1]=VV[0]; PP[1]=PP[0]; VV[0]=(v); PP[0]=(p); } \
          else { VV[1]=(v); PP[1]=(p); } } \
        else { VV[2]=(v); PP[2]=(p); } } \
      else { VV[3]=(v); PP[3]=(p); } } \
    else { VV[4]=(v); PP[4]=(p); } } } while(0)

// register-tiled gram: grid = 160 groups x 8 row-tiles(64 rows), 128 threads.
// thread = 4 rows x 16 cols; K=128 staged in 32-chunks. Top-5 per thread-slice
// kept in registers across col-chunks; one shfl_xor merge (tx: 3 steps) at end.
__global__ __launch_bounds__(128, 2) void k_gram(const float* __restrict__ enc,
        const int* __restrict__ sortedIdx, int* __restrict__ wsDst,
        float* __restrict__ wsVal, float* __restrict__ out) {
    __shared__ __align__(16) float As[32][64];    // [k][row]      8 KB
    __shared__ __align__(16) float Bs[32][128];   // [k][col swz] 16 KB
    __shared__ int gIdx[500];
    const int tid = threadIdx.x;
    const int grp = blockIdx.x >> 3;        // 0..159
    const int rowTile = blockIdx.x & 7;     // 8 tiles of 64 rows (500 padded to 512)
    const int b = grp / NBINS, g = grp % NBINS;
    const int tx = tid & 7;                 // col group: cols tx*16..tx*16+15
    const int ty = tid >> 3;                // row group: rows ty*4..ty*4+3
    for (int i = tid; i < 500; i += 128) gIdx[i] = sortedIdx[b*NPTS + g*500 + i];
    __syncthreads();

    const int rowBase = rowTile * 64;
    float tkv[4][5]; int tkp[4][5];
    #pragma unroll
    for (int er = 0; er < 4; ++er)
        #pragma unroll
        for (int j = 0; j < 5; ++j) { tkv[er][j] = -3.4e38f; tkp[er][j] = 0x7fffffff; }

    const int rotq = (tx >> 1) & 3;         // B bank-swizzle rotation (in quads)
    // staging assignments
    const int sRow = tid >> 1;              // A: row 0..63 (2 threads/row)
    const int sKh  = (tid & 1) * 16;        // A: k-half
    const size_t encBase = (size_t)b * NPTS * 128;
    const float* encA = enc + encBase + (size_t)gIdx[min(rowBase + sRow, 499)] * 128;
    // B staging swizzle for this thread's column slot (col-within-tile = tid)
    const int bi0 = tid & 15, btx = tid >> 4;
    const int c_sw = (tid & ~15) | ((bi0 + 4*(btx >> 1)) & 15);

    #pragma unroll 1
    for (int ch = 0; ch < 4; ++ch) {
        float acc[4][16];
        #pragma unroll
        for (int er = 0; er < 4; ++er)
            #pragma unroll
            for (int ec = 0; ec < 16; ++ec) acc[er][ec] = 0.f;
        const float* encB = enc + encBase + (size_t)gIdx[min(ch*128 + tid, 499)] * 128;
        #pragma unroll 1
        for (int kc = 0; kc < 128; kc += 32) {
            __syncthreads();   // previous chunk's reads done
            { // stage A: 64 rows x 32 k  (transpose to [k][row])
                float4 v0 = *(const float4*)(encA + kc + sKh + 0);
                float4 v1 = *(const float4*)(encA + kc + sKh + 4);
                float4 v2 = *(const float4*)(encA + kc + sKh + 8);
                float4 v3 = *(const float4*)(encA + kc + sKh + 12);
                As[sKh+ 0][sRow]=v0.x; As[sKh+ 1][sRow]=v0.y; As[sKh+ 2][sRow]=v0.z; As[sKh+ 3][sRow]=v0.w;
                As[sKh+ 4][sRow]=v1.x; As[sKh+ 5][sRow]=v1.y; As[sKh+ 6][sRow]=v1.z; As[sKh+ 7][sRow]=v1.w;
                As[sKh+ 8][sRow]=v2.x; As[sKh+ 9][sRow]=v2.y; As[sKh+10][sRow]=v2.z; As[sKh+11][sRow]=v2.w;
                As[sKh+12][sRow]=v3.x; As[sKh+13][sRow]=v3.y; As[sKh+14][sRow]=v3.z; As[sKh+15][sRow]=v3.w;
            }
            { // stage B: 128 cols x 32 k (transpose, swizzled col slot)
                #pragma unroll
                for (int q = 0; q < 8; ++q) {
                    float4 v = *(const float4*)(encB + kc + q*4);
                    Bs[q*4+0][c_sw]=v.x; Bs[q*4+1][c_sw]=v.y; Bs[q*4+2][c_sw]=v.z; Bs[q*4+3][c_sw]=v.w;
                }
            }
            __syncthreads();
            #pragma unroll 4
            for (int k = 0; k < 32; ++k) {
                float4 a4 = *(const float4*)&As[k][ty*4];
                float av[4] = {a4.x, a4.y, a4.z, a4.w};
                #pragma unroll
                for (int j = 0; j < 4; ++j) {
                    int q = (j + rotq) & 3;                      // de-swizzle
                    float4 b4 = *(const float4*)&Bs[k][tx*16 + q*4];
                    float bv[4] = {b4.x, b4.y, b4.z, b4.w};
                    #pragma unroll
                    for (int er = 0; er < 4; ++er)
                        #pragma unroll
                        for (int m = 0; m < 4; ++m)
                            acc[er][m + j*4] += av[er] * bv[m];
                }
            }
        }
        // fold this chunk into running per-thread top-5 (ascending cpos -> strict >)
        #pragma unroll
        for (int er = 0; er < 4; ++er) {
            #pragma unroll
            for (int ec = 0; ec < 16; ++ec) {
                int cpos = ch*128 + tx*16 + ec;
                float v = acc[er][ec];
                if (cpos < 500) INS_STRICT(tkv[er], tkp[er], v, cpos);
            }
        }
    }
    // merge across the 8 tx lanes (3 xor steps), tie-aware
    #pragma unroll
    for (int m = 1; m < 8; m <<= 1) {
        #pragma unroll
        for (int er = 0; er < 4; ++er) {
            float pv[5]; int pp[5];
            #pragma unroll
            for (int j = 0; j < 5; ++j) {
                pv[j] = __shfl_xor(tkv[er][j], m, 64);
                pp[j] = __shfl_xor(tkp[er][j], m, 64);
            }
            #pragma unroll
            for (int j = 0; j < 5; ++j) INS_TIE(tkv[er], tkp[er], pv[j], pp[j]);
        }
    }
    if (tx != 0) return;
    #pragma unroll
    for (int er = 0; er < 4; ++er) {
        int rpos = rowBase + ty*4 + er;
        if (rpos >= 500) continue;
        int src = gIdx[rpos];
        int dd[5]; float vv[5];
        #pragma unroll
        for (int j = 0; j < 5; ++j) {
            dd[j] = gIdx[tkp[er][j]];
            vv[j] = 1.f/(1.f + expf(-tkv[er][j]));
        }
        #define CSWAP(i,j) { if (dd[i] > dd[j]) { int td=dd[i];dd[i]=dd[j];dd[j]=td; \
                             float tf=vv[i];vv[i]=vv[j];vv[j]=tf; } }
        CSWAP(0,1) CSWAP(3,4) CSWAP(2,4) CSWAP(2,3) CSWAP(1,4)
        CSWAP(0,3) CSWAP(0,2) CSWAP(1,3) CSWAP(1,2)
        #undef CSWAP
        int base = b*EDGES_PER_BATCH + src*5;
        #pragma unroll
        for (int e = 0; e < 5; ++e) {
            wsDst[base+e] = dd[e];
            wsVal[base+e] = vv[e];
            out[EDGE_TOT   + base + e] = (float)src;
            out[2*EDGE_TOT + base + e] = (float)dd[e];
        }
    }
}

// edge MLP: one thread handles the 5 edges of one src (shares x_src partial)
__global__ __launch_bounds__(256) void k_edge(const float* __restrict__ X,
        const float* __restrict__ W1, const float* __restrict__ b1,
        const float* __restrict__ W2, const float* __restrict__ b2,
        const int* __restrict__ wsDst, const float* __restrict__ wsVal,
        float* __restrict__ out) {
    __shared__ float w1t[128*36];
    __shared__ float b1l[128];
    __shared__ float w2l[128];
    const int tid = threadIdx.x;
    for (int idx = tid; idx < 33*128; idx += 256) {
        int f = idx >> 7, j = idx & 127;
        w1t[j*36 + f] = W1[idx];
    }
    if (tid < 128) { b1l[tid] = b1[tid]; w2l[tid] = W2[tid]; }
    __syncthreads();
    int s = blockIdx.x*256 + tid;
    if (s >= TOTPTS) return;
    const int b = s / NPTS;
    const int sl = s % NPTS;
    const int base = b*EDGES_PER_BATCH + sl*5;
    float4 xs[4];
    {
        const float4* xp = (const float4*)(X + (size_t)s*NFEAT);
        #pragma unroll
        for (int q = 0; q < 4; ++q) xs[q] = xp[q];
    }
    int dste[5]; float vale[5]; float4 xd[5][4];
    #pragma unroll
    for (int e = 0; e < 5; ++e) {
        dste[e] = wsDst[base+e];
        vale[e] = wsVal[base+e];
        const float4* xp = (const float4*)(X + (size_t)(b*NPTS + dste[e])*NFEAT);
        #pragma unroll
        for (int q = 0; q < 4; ++q) xd[e][q] = xp[q];
    }
    float acc[5] = {0.f,0.f,0.f,0.f,0.f};
    for (int j = 0; j < 128; ++j) {
        const float* wr = &w1t[j*36];
        float sh = b1l[j];
        #pragma unroll
        for (int q = 0; q < 4; ++q) {
            float4 w = ((const float4*)wr)[q];
            sh += xs[q].x*w.x + xs[q].y*w.y + xs[q].z*w.z + xs[q].w*w.w;
        }
        float w32 = wr[32];
        float w2j = w2l[j];
        #pragma unroll
        for (int e = 0; e < 5; ++e) {
            float h = sh;
            #pragma unroll
            for (int q = 0; q < 4; ++q) {
                float4 w = ((const float4*)(wr+16))[q];
                h += xd[e][q].x*w.x + xd[e][q].y*w.y + xd[e][q].z*w.z + xd[e][q].w*w.w;
            }
            h += vale[e]*w32;
            h = (h > 0.f) ? h : expm1f(h);
            acc[e] += h * w2j;
        }
    }
    float b2v = b2[0];
    #pragma unroll
    for (int e = 0; e < 5; ++e) {
        out[base + e] = 1.f/(1.f + expf(-(acc[e] + b2v)));
    }
}

extern "C" void kernel_launch(void* const* d_in, const int* in_sizes, int n_in,
                              void* d_out, int out_size, void* d_ws, size_t ws_size,
                              hipStream_t stream) {
    const float* X   = (const float*)d_in[0];
    const float* We1 = (const float*)d_in[1];
    const float* be1 = (const float*)d_in[2];
    const float* We2 = (const float*)d_in[3];
    const float* be2 = (const float*)d_in[4];
    const float* Wd1 = (const float*)d_in[5];
    const float* bd1 = (const float*)d_in[6];
    const float* Wd2 = (const float*)d_in[7];
    const float* bd2 = (const float*)d_in[8];
    const float* R   = (const float*)d_in[9];
    float* out = (float*)d_out;

    float* enc      = (float*)d_ws;                       // 80000*128 f32
    int*   binIdx   = (int*)(enc + (size_t)TOTPTS*128);   // 80000
    int*   sortedIdx= binIdx + TOTPTS;                    // 80000
    int*   hist     = sortedIdx + TOTPTS;                 // 160
    int*   wsDst    = hist + NBATCH*NBINS;                // 400000
    float* wsVal    = (float*)(wsDst + EDGE_TOT);         // 400000

    k_zero_hist<<<1, 256, 0, stream>>>(hist);
    k_enc <<<TOTPTS/32, 256, 0, stream>>>(X, We1, be1, We2, be2, enc);
    k_bins<<<(TOTPTS+255)/256, 256, 0, stream>>>(enc, R, binIdx, hist);
    k_sort<<<NBATCH*NBINS, 256, 0, stream>>>(binIdx, hist, sortedIdx);
    k_gram<<<NBATCH*NBINS*8, 128, 0, stream>>>(enc, sortedIdx, wsDst, wsVal, out);
    k_edge<<<(TOTPTS+255)/256, 256, 0, stream>>>(X, Wd1, bd1, Wd2, bd2, wsDst, wsVal, out);
}

// Round 3
// 585.017 us; speedup vs baseline: 1.4350x; 1.0247x over previous
//
#include <hip/hip_runtime.h>
#include <cmath>

#define NPTS 10000
#define NBATCH 8
#define NFEAT 16
#define DDIM 128
#define NBINS 20
#define BINSZ 500
#define KSEL 5
#define EDGES_PER_BATCH (NPTS*KSEL)        // 50000
#define EDGE_TOT (NBATCH*EDGES_PER_BATCH)  // 400000
#define TOTPTS (NBATCH*NPTS)               // 80000

__global__ void k_zero_hist(int* hist) {
    int t = threadIdx.x;
    if (t < NBATCH*NBINS) hist[t] = 0;
}

// enc = ELU(X@W1+b1)@W2+b2 ; 32 points per block, 256 threads
__global__ __launch_bounds__(256) void k_enc(const float* __restrict__ X,
        const float* __restrict__ W1, const float* __restrict__ b1,
        const float* __restrict__ W2, const float* __restrict__ b2,
        float* __restrict__ enc) {
    __shared__ float hT[128*36];
    const int tid = threadIdx.x;
    const int P0 = blockIdx.x * 32;
    #pragma unroll
    for (int i = 0; i < 16; ++i) {
        int idx = i*256 + tid;
        int p = idx >> 7;
        int j = idx & 127;
        const float* xr = X + (size_t)(P0 + p)*NFEAT;
        float h = b1[j];
        #pragma unroll
        for (int f = 0; f < 16; ++f) h += xr[f] * W1[f*128 + j];
        h = (h > 0.f) ? h : expm1f(h);
        hT[j*36 + p] = h;
    }
    __syncthreads();
    const int jt = tid & 31, pt = tid >> 5;
    const int j0 = jt*4, p0 = pt*4;
    float acc[4][4];
    #pragma unroll
    for (int ep = 0; ep < 4; ++ep)
        #pragma unroll
        for (int ej = 0; ej < 4; ++ej) acc[ep][ej] = b2[j0+ej];
    for (int k = 0; k < 128; ++k) {
        float4 hv = *(const float4*)&hT[k*36 + p0];
        float4 wv = *(const float4*)&W2[k*128 + j0];
        float hvv[4] = {hv.x,hv.y,hv.z,hv.w};
        float wvv[4] = {wv.x,wv.y,wv.z,wv.w};
        #pragma unroll
        for (int ep = 0; ep < 4; ++ep)
            #pragma unroll
            for (int ej = 0; ej < 4; ++ej) acc[ep][ej] += hvv[ep]*wvv[ej];
    }
    #pragma unroll
    for (int ep = 0; ep < 4; ++ep) {
        float4 o = {acc[ep][0],acc[ep][1],acc[ep][2],acc[ep][3]};
        *(float4*)&enc[(size_t)(P0+p0+ep)*128 + j0] = o;
    }
}

// mul = enc @ R[:, :10]; bin = argmax([mul, -mul]) first-max-wins; histogram
__global__ __launch_bounds__(256) void k_bins(const float* __restrict__ enc,
        const float* __restrict__ R, int* __restrict__ binIdx, int* __restrict__ hist) {
    __shared__ float Rl[128*10];
    const int tid = threadIdx.x;
    for (int idx = tid; idx < 1280; idx += 256) {
        int d = idx / 10, i = idx % 10;
        Rl[idx] = R[d*100 + i];
    }
    __syncthreads();
    int gp = blockIdx.x*256 + tid;
    if (gp >= TOTPTS) return;
    float acc[10];
    #pragma unroll
    for (int i = 0; i < 10; ++i) acc[i] = 0.f;
    const float4* er = (const float4*)(enc + (size_t)gp*128);
    for (int d4 = 0; d4 < 32; ++d4) {
        float4 e4 = er[d4];
        float ev[4] = {e4.x,e4.y,e4.z,e4.w};
        #pragma unroll
        for (int q = 0; q < 4; ++q) {
            const float* rr = &Rl[(d4*4+q)*10];
            #pragma unroll
            for (int i = 0; i < 10; ++i) acc[i] += ev[q]*rr[i];
        }
    }
    float best = acc[0]; int bi = 0;
    #pragma unroll
    for (int i = 1; i < 10; ++i) if (acc[i] > best) { best = acc[i]; bi = i; }
    #pragma unroll
    for (int i = 0; i < 10; ++i) { float v = -acc[i]; if (v > best) { best = v; bi = 10+i; } }
    binIdx[gp] = bi;
    atomicAdd(&hist[(gp/NPTS)*NBINS + bi], 1);
}

// stable counting-sort scatter: one block per (batch,bin)
__global__ __launch_bounds__(256) void k_sort(const int* __restrict__ binIdx,
        const int* __restrict__ hist, int* __restrict__ sortedIdx) {
    const int b = blockIdx.x / NBINS;
    const int bin = blockIdx.x % NBINS;
    const int tid = threadIdx.x;
    __shared__ int wtot[4];
    int off = 0;
    for (int k = 0; k < bin; ++k) off += hist[b*NBINS + k];
    const int* bptr = binIdx + b*NPTS;
    int* sptr = sortedIdx + b*NPTS;
    const int lane = tid & 63, wid = tid >> 6;
    for (int c = 0; c < 40; ++c) {
        int i = c*256 + tid;
        bool pred = (i < NPTS) && (bptr[i] == bin);
        unsigned long long mask = __ballot(pred);
        int rank = __popcll(mask & ((1ULL << lane) - 1ULL));
        if (lane == 0) wtot[wid] = __popcll(mask);
        __syncthreads();
        int prefix = 0;
        #pragma unroll
        for (int w = 0; w < 4; ++w) prefix += (w < wid) ? wtot[w] : 0;
        int total = wtot[0]+wtot[1]+wtot[2]+wtot[3];
        if (pred) sptr[off + prefix + rank] = i;
        off += total;
        __syncthreads();
    }
}

// insert (v,p) into sorted-desc 5-list, strict > (candidates arrive in ascending p)
#define INS_STRICT(VV,PP,v,p) do { \
  if ((v) > VV[4]) { \
    if ((v) > VV[3]) { VV[4]=VV[3]; PP[4]=PP[3]; \
      if ((v) > VV[2]) { VV[3]=VV[2]; PP[3]=PP[2]; \
        if ((v) > VV[1]) { VV[2]=VV[1]; PP[2]=PP[1]; \
          if ((v) > VV[0]) { VV[1]=VV[0]; PP[1]=PP[0]; VV[0]=(v); PP[0]=(p); } \
          else { VV[1]=(v); PP[1]=(p); } } \
        else { VV[2]=(v); PP[2]=(p); } } \
      else { VV[3]=(v); PP[3]=(p); } } \
    else { VV[4]=(v); PP[4]=(p); } } } while(0)

// tie-aware better-than: (v desc, p asc) — exact lax.top_k semantics
#define BT(va,pa,vb,pb) (((va) > (vb)) || (((va) == (vb)) && ((pa) < (pb))))
#define INS_TIE(VV,PP,v,p) do { \
  if (BT(v,p,VV[4],PP[4])) { \
    if (BT(v,p,VV[3],PP[3])) { VV[4]=VV[3]; PP[4]=PP[3]; \
      if (BT(v,p,VV[2],PP[2])) { VV[3]=VV[2]; PP[3]=PP[2]; \
        if (BT(v,p,VV[1],PP[1])) { VV[2]=VV[1]; PP[2]=PP[1]; \
          if (BT(v,p,VV[0],PP[0])) { VV[1]=VV[0]; PP[1]=PP[0]; VV[0]=(v); PP[0]=(p); } \
          else { VV[1]=(v); PP[1]=(p); } } \
        else { VV[2]=(v); PP[2]=(p); } } \
      else { VV[3]=(v); PP[3]=(p); } } \
    else { VV[4]=(v); PP[4]=(p); } } } while(0)

// register-tiled gram. blockIdx = rowTile*160 + grp (160%8==0 => the 8 row-tile
// blocks of a group share an XCD => group B-panel fetched once per XCD's L2).
// Software-pipelined staging: chunk s+1 global loads issued during chunk s compute.
__global__ __launch_bounds__(128, 2) void k_gram(const float* __restrict__ enc,
        const int* __restrict__ sortedIdx, int* __restrict__ wsDst,
        float* __restrict__ wsVal, float* __restrict__ out) {
    __shared__ __align__(16) float As[32][64];    // [k][row]      8 KB
    __shared__ __align__(16) float Bs[32][128];   // [k][col swz] 16 KB
    __shared__ int gIdx[500];
    const int tid = threadIdx.x;
    const int rowTile = blockIdx.x / 160;   // 0..7
    const int grp = blockIdx.x - rowTile*160;
    const int b = grp / NBINS, g = grp % NBINS;
    const int tx = tid & 7;                 // col group: cols tx*16..tx*16+15
    const int ty = tid >> 3;                // row group: rows ty*4..ty*4+3
    for (int i = tid; i < 500; i += 128) gIdx[i] = sortedIdx[b*NPTS + g*500 + i];
    __syncthreads();

    const int rowBase = rowTile * 64;
    float tkv[4][5]; int tkp[4][5];
    #pragma unroll
    for (int er = 0; er < 4; ++er)
        #pragma unroll
        for (int j = 0; j < 5; ++j) { tkv[er][j] = -3.4e38f; tkp[er][j] = 0x7fffffff; }

    const int rotq = (tx >> 1) & 3;         // B bank-swizzle rotation (in quads)
    const int sRow = tid >> 1;              // A staging: row 0..63 (2 threads/row)
    const int sKh  = (tid & 1) * 16;        // A staging: k-half
    const size_t encBase = (size_t)b * NPTS * 128;
    const float* encA = enc + encBase + (size_t)gIdx[min(rowBase + sRow, 499)] * 128;
    const int bi0 = tid & 15, btx = tid >> 4;
    const int c_sw = (tid & ~15) | ((bi0 + 4*(btx >> 1)) & 15);  // B col slot swizzle

    float acc[4][16];
    float4 pa0, pa1, pa2, pa3; float4 pb[8];
    { // prefetch stage 0 (ch=0, kc=0)
        const float* eA = encA + sKh;
        pa0 = *(const float4*)(eA + 0); pa1 = *(const float4*)(eA + 4);
        pa2 = *(const float4*)(eA + 8); pa3 = *(const float4*)(eA + 12);
        const float* eB = enc + encBase + (size_t)gIdx[min(tid, 499)] * 128;
        #pragma unroll
        for (int q = 0; q < 8; ++q) pb[q] = *(const float4*)(eB + q*4);
    }

    #pragma unroll 1
    for (int s = 0; s < 16; ++s) {          // s = ch*4 + kc/32
        if ((s & 3) == 0) {
            #pragma unroll
            for (int er = 0; er < 4; ++er)
                #pragma unroll
                for (int ec = 0; ec < 16; ++ec) acc[er][ec] = 0.f;
        }
        __syncthreads();   // previous chunk's LDS reads done
        // store prefetched regs -> LDS (A transposed, B transposed+swizzled)
        As[sKh+ 0][sRow]=pa0.x; As[sKh+ 1][sRow]=pa0.y; As[sKh+ 2][sRow]=pa0.z; As[sKh+ 3][sRow]=pa0.w;
        As[sKh+ 4][sRow]=pa1.x; As[sKh+ 5][sRow]=pa1.y; As[sKh+ 6][sRow]=pa1.z; As[sKh+ 7][sRow]=pa1.w;
        As[sKh+ 8][sRow]=pa2.x; As[sKh+ 9][sRow]=pa2.y; As[sKh+10][sRow]=pa2.z; As[sKh+11][sRow]=pa2.w;
        As[sKh+12][sRow]=pa3.x; As[sKh+13][sRow]=pa3.y; As[sKh+14][sRow]=pa3.z; As[sKh+15][sRow]=pa3.w;
        #pragma unroll
        for (int q = 0; q < 8; ++q) {
            Bs[q*4+0][c_sw]=pb[q].x; Bs[q*4+1][c_sw]=pb[q].y;
            Bs[q*4+2][c_sw]=pb[q].z; Bs[q*4+3][c_sw]=pb[q].w;
        }
        if (s < 15) {   // prefetch stage s+1 (hidden under compute below)
            const int ns = s + 1, nch = ns >> 2, nkc = (ns & 3) * 32;
            const float* eA = encA + nkc + sKh;
            pa0 = *(const float4*)(eA + 0); pa1 = *(const float4*)(eA + 4);
            pa2 = *(const float4*)(eA + 8); pa3 = *(const float4*)(eA + 12);
            const float* eB = enc + encBase + (size_t)gIdx[min(nch*128 + tid, 499)] * 128 + nkc;
            #pragma unroll
            for (int q = 0; q < 8; ++q) pb[q] = *(const float4*)(eB + q*4);
        }
        __syncthreads();
        #pragma unroll 4
        for (int k = 0; k < 32; ++k) {
            float4 a4 = *(const float4*)&As[k][ty*4];
            float av[4] = {a4.x, a4.y, a4.z, a4.w};
            #pragma unroll
            for (int j = 0; j < 4; ++j) {
                int q = (j + rotq) & 3;                      // de-swizzle
                float4 b4 = *(const float4*)&Bs[k][tx*16 + q*4];
                float bv[4] = {b4.x, b4.y, b4.z, b4.w};
                #pragma unroll
                for (int er = 0; er < 4; ++er)
                    #pragma unroll
                    for (int m = 0; m < 4; ++m)
                        acc[er][m + j*4] += av[er] * bv[m];
            }
        }
        if ((s & 3) == 3) {
            const int ch = s >> 2;
            #pragma unroll
            for (int er = 0; er < 4; ++er) {
                #pragma unroll
                for (int ec = 0; ec < 16; ++ec) {
                    int cpos = ch*128 + tx*16 + ec;
                    float v = acc[er][ec];
                    if (cpos < 500) INS_STRICT(tkv[er], tkp[er], v, cpos);
                }
            }
        }
    }
    // merge across the 8 tx lanes (3 xor steps), tie-aware
    #pragma unroll
    for (int m = 1; m < 8; m <<= 1) {
        #pragma unroll
        for (int er = 0; er < 4; ++er) {
            float pv[5]; int pp[5];
            #pragma unroll
            for (int j = 0; j < 5; ++j) {
                pv[j] = __shfl_xor(tkv[er][j], m, 64);
                pp[j] = __shfl_xor(tkp[er][j], m, 64);
            }
            #pragma unroll
            for (int j = 0; j < 5; ++j) INS_TIE(tkv[er], tkp[er], pv[j], pp[j]);
        }
    }
    if (tx != 0) return;
    #pragma unroll
    for (int er = 0; er < 4; ++er) {
        int rpos = rowBase + ty*4 + er;
        if (rpos >= 500) continue;
        int src = gIdx[rpos];
        int dd[5]; float vv[5];
        #pragma unroll
        for (int j = 0; j < 5; ++j) {
            dd[j] = gIdx[tkp[er][j]];
            vv[j] = 1.f/(1.f + expf(-tkv[er][j]));
        }
        #define CSWAP(i,j) { if (dd[i] > dd[j]) { int td=dd[i];dd[i]=dd[j];dd[j]=td; \
                             float tf=vv[i];vv[i]=vv[j];vv[j]=tf; } }
        CSWAP(0,1) CSWAP(3,4) CSWAP(2,4) CSWAP(2,3) CSWAP(1,4)
        CSWAP(0,3) CSWAP(0,2) CSWAP(1,3) CSWAP(1,2)
        #undef CSWAP
        int base = b*EDGES_PER_BATCH + src*5;
        #pragma unroll
        for (int e = 0; e < 5; ++e) {
            wsDst[base+e] = dd[e];
            wsVal[base+e] = vv[e];
            out[EDGE_TOT   + base + e] = (float)src;
            out[2*EDGE_TOT + base + e] = (float)dd[e];
        }
    }
}

// edge MLP: one thread handles the 5 edges of one src (shares x_src partial);
// w1t fragments hoisted out of the e-loop (9 b128 LDS reads per j, not 20+)
__global__ __launch_bounds__(256) void k_edge(const float* __restrict__ X,
        const float* __restrict__ W1, const float* __restrict__ b1,
        const float* __restrict__ W2, const float* __restrict__ b2,
        const int* __restrict__ wsDst, const float* __restrict__ wsVal,
        float* __restrict__ out) {
    __shared__ float w1t[128*36];
    __shared__ float b1l[128];
    __shared__ float w2l[128];
    const int tid = threadIdx.x;
    for (int idx = tid; idx < 33*128; idx += 256) {
        int f = idx >> 7, j = idx & 127;
        w1t[j*36 + f] = W1[idx];
    }
    if (tid < 128) { b1l[tid] = b1[tid]; w2l[tid] = W2[tid]; }
    __syncthreads();
    int s = blockIdx.x*256 + tid;
    if (s >= TOTPTS) return;
    const int b = s / NPTS;
    const int sl = s % NPTS;
    const int base = b*EDGES_PER_BATCH + sl*5;
    float4 xs[4];
    {
        const float4* xp = (const float4*)(X + (size_t)s*NFEAT);
        #pragma unroll
        for (int q = 0; q < 4; ++q) xs[q] = xp[q];
    }
    int dste[5]; float vale[5]; float4 xd[5][4];
    #pragma unroll
    for (int e = 0; e < 5; ++e) {
        dste[e] = wsDst[base+e];
        vale[e] = wsVal[base+e];
        const float4* xp = (const float4*)(X + (size_t)(b*NPTS + dste[e])*NFEAT);
        #pragma unroll
        for (int q = 0; q < 4; ++q) xd[e][q] = xp[q];
    }
    float acc[5] = {0.f,0.f,0.f,0.f,0.f};
    for (int j = 0; j < 128; ++j) {
        const float* wr = &w1t[j*36];
        float4 ws0 = ((const float4*)wr)[0];
        float4 ws1 = ((const float4*)wr)[1];
        float4 ws2 = ((const float4*)wr)[2];
        float4 ws3 = ((const float4*)wr)[3];
        float4 u0  = ((const float4*)(wr+16))[0];
        float4 u1  = ((const float4*)(wr+16))[1];
        float4 u2  = ((const float4*)(wr+16))[2];
        float4 u3  = ((const float4*)(wr+16))[3];
        float w32 = wr[32];
        float w2j = w2l[j];
        float sh = b1l[j]
            + xs[0].x*ws0.x + xs[0].y*ws0.y + xs[0].z*ws0.z + xs[0].w*ws0.w
            + xs[1].x*ws1.x + xs[1].y*ws1.y + xs[1].z*ws1.z + xs[1].w*ws1.w
            + xs[2].x*ws2.x + xs[2].y*ws2.y + xs[2].z*ws2.z + xs[2].w*ws2.w
            + xs[3].x*ws3.x + xs[3].y*ws3.y + xs[3].z*ws3.z + xs[3].w*ws3.w;
        #pragma unroll
        for (int e = 0; e < 5; ++e) {
            float h = sh
                + xd[e][0].x*u0.x + xd[e][0].y*u0.y + xd[e][0].z*u0.z + xd[e][0].w*u0.w
                + xd[e][1].x*u1.x + xd[e][1].y*u1.y + xd[e][1].z*u1.z + xd[e][1].w*u1.w
                + xd[e][2].x*u2.x + xd[e][2].y*u2.y + xd[e][2].z*u2.z + xd[e][2].w*u2.w
                + xd[e][3].x*u3.x + xd[e][3].y*u3.y + xd[e][3].z*u3.z + xd[e][3].w*u3.w;
            h += vale[e]*w32;
            h = (h > 0.f) ? h : expm1f(h);
            acc[e] += h * w2j;
        }
    }
    float b2v = b2[0];
    #pragma unroll
    for (int e = 0; e < 5; ++e) {
        out[base + e] = 1.f/(1.f + expf(-(acc[e] + b2v)));
    }
}

extern "C" void kernel_launch(void* const* d_in, const int* in_sizes, int n_in,
                              void* d_out, int out_size, void* d_ws, size_t ws_size,
                              hipStream_t stream) {
    const float* X   = (const float*)d_in[0];
    const float* We1 = (const float*)d_in[1];
    const float* be1 = (const float*)d_in[2];
    const float* We2 = (const float*)d_in[3];
    const float* be2 = (const float*)d_in[4];
    const float* Wd1 = (const float*)d_in[5];
    const float* bd1 = (const float*)d_in[6];
    const float* Wd2 = (const float*)d_in[7];
    const float* bd2 = (const float*)d_in[8];
    const float* R   = (const float*)d_in[9];
    float* out = (float*)d_out;

    float* enc      = (float*)d_ws;                       // 80000*128 f32
    int*   binIdx   = (int*)(enc + (size_t)TOTPTS*128);   // 80000
    int*   sortedIdx= binIdx + TOTPTS;                    // 80000
    int*   hist     = sortedIdx + TOTPTS;                 // 160
    int*   wsDst    = hist + NBATCH*NBINS;                // 400000
    float* wsVal    = (float*)(wsDst + EDGE_TOT);         // 400000

    k_zero_hist<<<1, 256, 0, stream>>>(hist);
    k_enc <<<TOTPTS/32, 256, 0, stream>>>(X, We1, be1, We2, be2, enc);
    k_bins<<<(TOTPTS+255)/256, 256, 0, stream>>>(enc, R, binIdx, hist);
    k_sort<<<NBATCH*NBINS, 256, 0, stream>>>(binIdx, hist, sortedIdx);
    k_gram<<<NBATCH*NBINS*8, 128, 0, stream>>>(enc, sortedIdx, wsDst, wsVal, out);
    k_edge<<<(TOTPTS+255)/256, 256, 0, stream>>>(X, Wd1, bd1, Wd2, bd2, wsDst, wsVal, out);
}